// Round 5
// baseline (221.226 us; speedup 1.0000x reference)
//
#include <hip/hip_runtime.h>
#include <cstdint>
#include <cstddef>

// Established by rounds 0-4 forensics: inputs fp32, OUTPUT fp32.
//   dec: [16, 3999, 512] fp32, wgt: [16, 512] fp32, out: [16, 32000] fp32
//   est[f][w] = dot(dec[f], wgt[w]);  out[8g+i] = est[g][i] + est[g-1][8+i]
// Round-4 failure was (a) bf16 stores into fp32 buffer, (b) epilogue guard
// tid<504 with 256 threads leaving groups 32..62 unwritten. Both fixed.

#define NBC     16
#define FRAMES  3999
#define EE      512
#define TOUT    32000
#define NGROUP  4000
#define GPB     63      // output groups per block
#define KCH     64      // K-chunk staged per round
#define NKCH    8
#define XSTR    65      // xs row stride in floats (odd -> conflict-free b32)

// Block: 256 threads = 64 frame-slots (s) x 4 K-quarters (q).
// Block owns groups [g0, g0+62]; needs frames f = g0-1+s, s in [0,64).
// Thread (s,q): accumulates 16 est values for frame f(s) over its 16-k
// slice of each 64-k chunk; 4-way LDS reduction; fused overlap-add.

__global__ __launch_bounds__(256) void decoder_kernel(
    const float* __restrict__ dec,
    const float* __restrict__ wgt,
    float* __restrict__ out)
{
    __shared__ float wl[16 * EE];        // 32 KB: wl[w*512 + k]
    __shared__ float xs[64 * XSTR];      // 16.6 KB: xs[s*65 + k_local]

    const int tid   = threadIdx.x;
    const int bc    = blockIdx.x >> 6;   // 0..15
    const int chunk = blockIdx.x & 63;   // 0..63
    const int g0    = chunk * GPB;

    const float* decb = dec + (size_t)bc * (FRAMES * EE);

    // ---- stage weight into LDS (float4, coalesced; once) ----
    {
        const float4* ws = (const float4*)wgt;
        float4*       wd = (float4*)wl;
        #pragma unroll
        for (int i = 0; i < 8; ++i)
            wd[tid + 256 * i] = ws[tid + 256 * i];
    }

    const int s = tid & 63;
    const int q = tid >> 6;              // wave-uniform (wave = 64 threads)
    const int f = g0 - 1 + s;
    const float vmask = (f >= 0 && f < FRAMES) ? 1.0f : 0.0f;

    const int rs = tid >> 4;             // staging base row 0..15
    const int c4 = tid & 15;             // staging float4 col 0..15

    float acc[16];
    #pragma unroll
    for (int w = 0; w < 16; ++w) acc[w] = 0.f;

    for (int kk = 0; kk < NKCH; ++kk) {
        __syncthreads();                 // xs free (also orders wl stores)

        // ---- stage 64 frames x 64 floats (16 lanes x 16B contiguous/row) ----
        #pragma unroll
        for (int it = 0; it < 4; ++it) {
            const int r = rs + 16 * it;
            int fr = g0 - 1 + r;
            fr = min(max(fr, 0), FRAMES - 1);    // clamp; masked via vmask
            const float4 v =
                *(const float4*)(decb + (size_t)fr * EE + kk * KCH + 4 * c4);
            float* x = &xs[r * XSTR + 4 * c4];   // bank (r+4c4+e)%32: 2-way, free
            x[0] = v.x; x[1] = v.y; x[2] = v.z; x[3] = v.w;
        }
        __syncthreads();

        // ---- compute: k_local in [16q, 16q+16) ----
        float xv[16];
        #pragma unroll
        for (int u = 0; u < 16; ++u)
            xv[u] = xs[s * XSTR + 16 * q + u];   // bank (s+c)%32: 2-way, free
        #pragma unroll
        for (int w = 0; w < 16; ++w) {
            const float4* wrow =                  // wave-uniform -> broadcast
                (const float4*)&wl[w * EE + kk * KCH + 16 * q];
            float sum = 0.f;
            #pragma unroll
            for (int u = 0; u < 4; ++u) {
                const float4 wq = wrow[u];
                sum += xv[4*u+0]*wq.x + xv[4*u+1]*wq.y
                     + xv[4*u+2]*wq.z + xv[4*u+3]*wq.w;
            }
            acc[w] += sum;
        }
    }

    // ---- 4-way K-split reduction via LDS, fused overlap-add, fp32 store ----
    __syncthreads();                     // done reading xs
    float* red = xs;                     // red[(q*16+w)*64 + s], 4096 <= 4160
    #pragma unroll
    for (int w = 0; w < 16; ++w)
        red[(q * 16 + w) * 64 + s] = acc[w] * vmask;
    __syncthreads();

    // 504 outputs per block, 256 threads -> 2 strided iterations
    for (int o = tid; o < GPB * 8; o += 256) {
        const int j = o >> 3;            // group offset in block, 0..62
        const int i = o & 7;             // sample within group
        const int g = g0 + j;
        if (g < NGROUP) {
            float v = 0.f;
            #pragma unroll
            for (int qq = 0; qq < 4; ++qq)
                v += red[(qq * 16 + i) * 64 + (j + 1)]      // est[g][i]
                   + red[(qq * 16 + 8 + i) * 64 + j];       // est[g-1][8+i]
            out[(size_t)bc * TOUT + g * 8 + i] = v;
        }
    }
}

extern "C" void kernel_launch(void* const* d_in, const int* in_sizes, int n_in,
                              void* d_out, int out_size, void* d_ws, size_t ws_size,
                              hipStream_t stream) {
    const float* dec = (const float*)d_in[0];   // [8,2,3999,512] fp32
    const float* wgt = (const float*)d_in[1];   // [16,512] fp32
    float* out = (float*)d_out;                 // [8,2,32000] fp32

    decoder_kernel<<<dim3(1024), dim3(256), 0, stream>>>(dec, wgt, out);
}

// Round 6
// 196.767 us; speedup vs baseline: 1.1243x; 1.1243x over previous
//
#include <hip/hip_runtime.h>
#include <cstdint>
#include <cstddef>

// dec: [16, 3999, 512] fp32, wgt: [16, 512] fp32, out: [16, 32000] fp32
//   est[f][w] = dot(dec[f], wgt[w]);  out[8g+i] = est[g][i] + est[g-1][8+i]
//
// R6 structure: no x-staging, no per-chunk barriers. Thread (s,q) reads its
// frame's K-quarter straight from global (each 64B line consumed entirely by
// one lane); weight broadcast from LDS; 4-way K reduction + fused overlap-add
// in an LDS buffer overlaid on the weight region (32 KB total -> 4 blocks/CU).

#define NBC     16
#define FRAMES  3999
#define EE      512
#define TOUT    32000
#define NGROUP  4000
#define GPB     63      // output groups per block (64 frame-slots)

__global__ __launch_bounds__(256, 4) void decoder_kernel(
    const float* __restrict__ dec,
    const float* __restrict__ wgt,
    float* __restrict__ out)
{
    __shared__ float smem[16 * EE];      // 32 KB: weight, later reduction buf
    float* wl  = smem;                   // wl[w*512 + k]
    float* red = smem;                   // red[(q*16+w)*64 + s], 16 KB overlay

    const int tid   = threadIdx.x;
    const int bc    = blockIdx.x >> 6;   // 0..15
    const int chunk = blockIdx.x & 63;   // 0..63
    const int g0    = chunk * GPB;

    // ---- stage weight into LDS (float4, coalesced; once) ----
    {
        const float4* ws = (const float4*)wgt;
        float4*       wd = (float4*)wl;
        #pragma unroll
        for (int i = 0; i < 8; ++i)
            wd[tid + 256 * i] = ws[tid + 256 * i];
    }
    __syncthreads();

    const int s = tid & 63;              // frame slot
    const int q = tid >> 6;              // K-quarter (wave-uniform)
    const int f = g0 - 1 + s;
    const float vmask = (f >= 0 && f < FRAMES) ? 1.0f : 0.0f;
    const int fr = min(max(f, 0), FRAMES - 1);   // clamped row for safe loads

    // this thread's contiguous K-quarter of its frame
    const float* arow = dec + ((size_t)bc * FRAMES + fr) * EE + q * 128;
    const float* wbase = wl + q * 128;   // wave-uniform

    float acc[16];
    #pragma unroll
    for (int w = 0; w < 16; ++w) acc[w] = 0.f;

    // 8 sub-chunks of 16 k; no barriers -> loads pipeline across iterations
    #pragma unroll
    for (int c = 0; c < 8; ++c) {
        float4 xv[4];
        #pragma unroll
        for (int u = 0; u < 4; ++u)
            xv[u] = *(const float4*)(arow + c * 16 + 4 * u);   // one 64B line

        #pragma unroll
        for (int w = 0; w < 16; ++w) {
            const float4* wrow = (const float4*)(wbase + w * EE + c * 16);
            float sum = 0.f;
            #pragma unroll
            for (int u = 0; u < 4; ++u) {
                const float4 wq = wrow[u];                     // LDS broadcast
                sum += xv[u].x * wq.x + xv[u].y * wq.y
                     + xv[u].z * wq.z + xv[u].w * wq.w;
            }
            acc[w] += sum;
        }
    }

    // ---- 4-way K-split reduction (red overlays wl) ----
    __syncthreads();                     // all weight reads done
    #pragma unroll
    for (int w = 0; w < 16; ++w)
        red[(q * 16 + w) * 64 + s] = acc[w] * vmask;
    __syncthreads();

    // ---- fused overlap-add: 504 outputs, 256 threads -> 2 iterations ----
    for (int o = tid; o < GPB * 8; o += 256) {
        const int j = o >> 3;            // group offset in block, 0..62
        const int i = o & 7;             // sample within group
        const int g = g0 + j;
        if (g < NGROUP) {
            float v = 0.f;
            #pragma unroll
            for (int qq = 0; qq < 4; ++qq)
                v += red[(qq * 16 + i) * 64 + (j + 1)]      // est[g][i]
                   + red[(qq * 16 + 8 + i) * 64 + j];       // est[g-1][8+i]
            out[(size_t)bc * TOUT + g * 8 + i] = v;
        }
    }
}

extern "C" void kernel_launch(void* const* d_in, const int* in_sizes, int n_in,
                              void* d_out, int out_size, void* d_ws, size_t ws_size,
                              hipStream_t stream) {
    const float* dec = (const float*)d_in[0];   // [8,2,3999,512] fp32
    const float* wgt = (const float*)d_in[1];   // [16,512] fp32
    float* out = (float*)d_out;                 // [8,2,32000] fp32

    decoder_kernel<<<dim3(1024), dim3(256), 0, stream>>>(dec, wgt, out);
}